// Round 6
// baseline (337.277 us; speedup 1.0000x reference)
//
#include <hip/hip_runtime.h>
#include <hip/hip_bf16.h>

using bf16 = __hip_bfloat16;
using short8 = __attribute__((ext_vector_type(8))) short;
using f32x4  = __attribute__((ext_vector_type(4))) float;
typedef unsigned int u32;

#define LAT_ 1536

__device__ __forceinline__ void glds16(const bf16* g, bf16* l) {
  __builtin_amdgcn_global_load_lds(
      (const __attribute__((address_space(1))) void*)g,
      (__attribute__((address_space(3))) void*)l, 16, 0, 0);
}
__device__ __forceinline__ float b2f(bf16 x) { return __bfloat162float(x); }
__device__ __forceinline__ bf16 f2b(float x) { return __float2bfloat16(x); }

// ---------------- packA: Wp[3072][1536] bf16 ----------------
// rows 0-511 g_Wi | 512-1023 g_Wj | 1024-1535 p_Wi | 1536-2047 p_Wj | 2048-2559 g_We | 2560-3071 p_We
__global__ __launch_bounds__(256) void packA_k(const float* __restrict__ g_iw,
                                               const float* __restrict__ p_iw,
                                               bf16* __restrict__ Wp) {
  int seg = blockIdx.y;
  int idx = blockIdx.x * 256 + threadIdx.x;
  if (idx >= 512 * 1536) return;
  int r = idx / 1536, c = idx % 1536;
  const float* src; int co;
  switch (seg) {
    case 0: src = g_iw; co = 0;    break;
    case 1: src = g_iw; co = 1536; break;
    case 2: src = p_iw; co = 0;    break;
    case 3: src = p_iw; co = 1536; break;
    case 4: src = g_iw; co = 3072; break;
    default: src = p_iw; co = 3072; break;
  }
  Wp[(long)seg * 512 * 1536 + idx] = f2b(src[(long)r * 4608 + co + c]);
}

// ---------------- packB: p_cw/p_ow/T5 bf16, bn consts, pair table, u ----------------
__global__ __launch_bounds__(256) void packB_k(
    const float* __restrict__ p_cw, const float* __restrict__ p_ow, const float* __restrict__ f5,
    const float* __restrict__ g_bg, const float* __restrict__ g_bb, const float* __restrict__ g_bm,
    const float* __restrict__ g_bv, const float* __restrict__ p_bg, const float* __restrict__ p_bb,
    const float* __restrict__ p_bm, const float* __restrict__ p_bv,
    const float* __restrict__ g_ib, const float* __restrict__ p_ib, const float* __restrict__ p_cb,
    const float* __restrict__ g_ow, const float* __restrict__ g_cw,
    bf16* __restrict__ pcw16, bf16* __restrict__ pow16, bf16* __restrict__ T5,
    float* __restrict__ bnp, int* __restrict__ PAIR, float* __restrict__ u) {
  int idx = blockIdx.x * 256 + threadIdx.x;
  if (blockIdx.y == 0) {
    if (idx < 262144) pcw16[idx] = f2b(p_cw[idx]);
    return;
  }
  if (idx < 32768) { pow16[idx] = f2b(p_ow[idx]); return; }
  if (idx < 36864) { int e = idx - 32768; T5[e] = f2b(f5[e]); return; }
  if (idx < 37376) {
    int k = idx - 36864;
    float sg = g_bg[k] / sqrtf(g_bv[k] + 1e-5f);
    bnp[k] = sg; bnp[512 + k] = g_bb[k] - g_bm[k] * sg;
    float sp = p_bg[k] / sqrtf(p_bv[k] + 1e-5f);
    bnp[1024 + k] = sp; bnp[1536 + k] = p_bb[k] - p_bm[k] * sp;
    bnp[2048 + k] = g_ib[k]; bnp[2560 + k] = p_ib[k];
    bnp[3584 + k] = p_cb[k];
    return;
  }
  if (idx < 37904) {
    int t = idx - 37376;                    // 0..527 -> (i<=j)
    int i = 0, rem = t;
    while (rem >= 32 - i) { rem -= 32 - i; ++i; }
    PAIR[t] = i * 32 + (i + rem);
    return;
  }
  if (idx < 38416) {
    int k = idx - 37904;                    // u[k] = sum_n g_ow[n]*g_cw[n][k]
    float s = 0.f;
    for (int n = 0; n < 512; ++n) s = fmaf(g_ow[n], g_cw[n * 512 + k], s);
    u[k] = s;
  }
}

// ---------------- NCHW fp32 -> NHWC bf16 transpose (all levels, one dispatch) ----------------
template<int C, int W>
__device__ __forceinline__ void trans_tile(const float* __restrict__ src, bf16* __restrict__ dst,
                                           int b, int hw0, int c0, bf16 (*tile)[72], int t) {
  constexpr int HW = W * W;
  {
    int cl = t >> 2, h0 = (t & 3) * 16;
    const float* sp = src + (long)(b * C + c0 + cl) * HW + hw0 + h0;
    #pragma unroll
    for (int k = 0; k < 16; k += 4) {
      float4 v = *(const float4*)(sp + k);
      tile[h0 + k + 0][cl] = f2b(v.x);
      tile[h0 + k + 1][cl] = f2b(v.y);
      tile[h0 + k + 2][cl] = f2b(v.z);
      tile[h0 + k + 3][cl] = f2b(v.w);
    }
  }
  __syncthreads();
  {
    int hwl = t >> 2, cc = (t & 3) * 16;
    bf16* dp = dst + ((long)b * HW + hw0 + hwl) * C + c0 + cc;
    #pragma unroll
    for (int k = 0; k < 16; k += 2) {
      __hip_bfloat162 pr;
      pr.x = tile[hwl][cc + k];
      pr.y = tile[hwl][cc + k + 1];
      *(__hip_bfloat162*)(dp + k) = pr;
    }
  }
}

__global__ __launch_bounds__(256) void transpose_all_k(
    const float* __restrict__ f0, const float* __restrict__ f1, const float* __restrict__ f2,
    const float* __restrict__ f3, const float* __restrict__ f4,
    bf16* __restrict__ T0, bf16* __restrict__ T1, bf16* __restrict__ T2,
    bf16* __restrict__ T3, bf16* __restrict__ T4) {
  __shared__ bf16 tile[64][72];
  int b = blockIdx.y, tt = blockIdx.x, t = threadIdx.x;
  if (tt < 256)      trans_tile<64, 128>(f0, T0, b, tt * 64, 0, tile, t);
  else if (tt < 320) trans_tile<64, 64 >(f1, T1, b, (tt - 256) * 64, 0, tile, t);
  else if (tt < 352) { int q = tt - 320; trans_tile<128, 32>(f2, T2, b, (q & 15) * 64, (q >> 4) * 64, tile, t); }
  else if (tt < 368) { int q = tt - 352; trans_tile<256, 16>(f3, T3, b, (q & 3) * 64, (q >> 2) * 64, tile, t); }
  else               { int q = tt - 368; trans_tile<512, 8 >(f4, T4, b, 0, q * 64, tile, t); }
}

// ---------------- sampling: Sb[b][m=560][k=1536] bf16 ----------------
__device__ __forceinline__ float blo(u32 r) { return __uint_as_float(r << 16); }
__device__ __forceinline__ float bhi(u32 r) { return __uint_as_float(r & 0xffff0000u); }

template<int C, int W>
__device__ __forceinline__ void proc2(const bf16* __restrict__ T, int b,
    const float* MX, const float* MY, bf16* __restrict__ Sb, int koff, int t) {
  constexpr int C2 = C / 2, HW = W * W;
  const bf16* Tb = T + (long)b * HW * C;
  for (int idx = t; idx < 16 * C2; idx += 256) {
    int q = idx / C2, c2 = idx % C2;
    float x = MX[q], y = MY[q];
    float fx = fminf(fmaxf(x * ((float)W / 256.f) - 0.5f, 0.f), (float)(W - 1));
    float fy = fminf(fmaxf(y * ((float)W / 256.f) - 0.5f, 0.f), (float)(W - 1));
    float x0f = floorf(fx), y0f = floorf(fy);
    float wx = fx - x0f, wy = fy - y0f;
    int x0 = (int)x0f, y0 = (int)y0f;
    int x1 = min(x0 + 1, W - 1), y1 = min(y0 + 1, W - 1);
    u32 r00 = *(const u32*)&Tb[(y0 * W + x0) * C + 2 * c2];
    u32 r01 = *(const u32*)&Tb[(y0 * W + x1) * C + 2 * c2];
    u32 r10 = *(const u32*)&Tb[(y1 * W + x0) * C + 2 * c2];
    u32 r11 = *(const u32*)&Tb[(y1 * W + x1) * C + 2 * c2];
    float w00 = (1.f - wx) * (1.f - wy), w01 = wx * (1.f - wy);
    float w10 = (1.f - wx) * wy,        w11 = wx * wy;
    float vlo = blo(r00) * w00 + blo(r01) * w01 + blo(r10) * w10 + blo(r11) * w11;
    float vhi = bhi(r00) * w00 + bhi(r01) * w01 + bhi(r10) * w10 + bhi(r11) * w11;
    __hip_bfloat162 pr;
    pr.x = f2b(vlo); pr.y = f2b(vhi);
    *(__hip_bfloat162*)&Sb[(long)q * LAT_ + koff + 2 * c2] = pr;
  }
}

__global__ __launch_bounds__(256) void sample4_k(
    const bf16* __restrict__ T0, const bf16* __restrict__ T1, const bf16* __restrict__ T2,
    const bf16* __restrict__ T3, const bf16* __restrict__ T4, const bf16* __restrict__ T5,
    const float* __restrict__ P, const int* __restrict__ PAIR, bf16* __restrict__ Sball) {
  int b = blockIdx.y, p0 = blockIdx.x * 16, t = threadIdx.x;
  __shared__ float Px[32], Py[32], MX[16], MY[16];
  if (t < 32) { Px[t] = P[(b * 32 + t) * 2]; Py[t] = P[(b * 32 + t) * 2 + 1]; }
  __syncthreads();
  if (t < 16) {
    int m = p0 + t;
    float x, y;
    if (m < 32) { x = Px[m]; y = Py[m]; }
    else { int pr_ = PAIR[m - 32]; int i = pr_ >> 5, j = pr_ & 31;
           x = 0.5f * (Px[i] + Px[j]); y = 0.5f * (Py[i] + Py[j]); }
    MX[t] = x; MY[t] = y;
  }
  __syncthreads();
  bf16* Sb = Sball + ((long)b * 560 + p0) * LAT_;
  proc2<64, 128>(T0, b, MX, MY, Sb, 0,    t);
  proc2<64, 64 >(T1, b, MX, MY, Sb, 64,   t);
  proc2<128, 32>(T2, b, MX, MY, Sb, 128,  t);
  proc2<256, 16>(T3, b, MX, MY, Sb, 256,  t);
  proc2<512, 8 >(T4, b, MX, MY, Sb, 512,  t);
  for (int idx = t; idx < 16 * 256; idx += 256) {
    int q = idx >> 8, c2 = idx & 255;
    *(__hip_bfloat162*)&Sb[(long)q * LAT_ + 1024 + 2 * c2] =
        *(const __hip_bfloat162*)&T5[b * 512 + 2 * c2];
  }
}

// ---------------- node GEMM: A4[b][32][2048] ----------------
__global__ __launch_bounds__(256) void nodegemm_k(
    const bf16* __restrict__ Sball, const bf16* __restrict__ Wp, float* __restrict__ A4) {
  int b = blockIdx.y;
  int n0 = blockIdx.x * 64;
  int t = threadIdx.x, w = t >> 6, lane = t & 63;
  int nn = n0 + w * 16;
  int frow = lane & 15, fko = (lane >> 4) * 8;
  const bf16* Ab = Sball + (long)b * 560 * LAT_;
  f32x4 acc[2] = {};
  for (int kb = 0; kb < LAT_; kb += 32) {
    short8 bq = *(const short8*)&Wp[(long)(nn + frow) * LAT_ + kb + fko];
    #pragma unroll
    for (int i = 0; i < 2; ++i) {
      short8 aq = *(const short8*)&Ab[(long)(i * 16 + frow) * LAT_ + kb + fko];
      acc[i] = __builtin_amdgcn_mfma_f32_16x16x32_bf16(aq, bq, acc[i], 0, 0, 0);
    }
  }
  #pragma unroll
  for (int i = 0; i < 2; ++i)
    #pragma unroll
    for (int r = 0; r < 4; ++r) {
      int m = i * 16 + (lane >> 4) * 4 + r;
      int n = nn + (lane & 15);
      A4[(long)b * 65536 + m * 2048 + n] = acc[i][r];
    }
}

// ---------------- edge GEMM (symmetric M=528), swizzled LDS ----------------
__global__ __launch_bounds__(256) void edge_k(
    const bf16* __restrict__ Sball, const bf16* __restrict__ WpE,
    const float* __restrict__ bnp, const float* __restrict__ A4,
    const int* __restrict__ PAIR,
    bf16* __restrict__ XFh, bf16* __restrict__ DH) {
  int b = blockIdx.z;
  int m0 = blockIdx.x * 128, n0 = blockIdx.y * 128;
  const bf16* A = Sball + (long)b * 560 * LAT_ + 32 * LAT_;
  __shared__ bf16 Ash[128 * 32];
  __shared__ bf16 Bsh[128 * 32];
  int t = threadIdx.x, w = t >> 6, lane = t & 63;
  int mh = (w & 1) * 64, nh = (w >> 1) * 64;
  int frow = lane & 15, cf = lane >> 4;
  int lrow = lane >> 2, lchunk = lane & 3;
  int csw = (lrow >> 1) & 3;
  int sA = (cf ^ ((frow >> 1) & 3)) * 8;
  f32x4 acc[4][4] = {};
  for (int kb = 0; kb < LAT_; kb += 32) {
    #pragma unroll
    for (int q = 0; q < 2; ++q) {
      int ra = q * 64 + w * 16 + lrow;
      int am = min(m0 + ra, 527);
      glds16(&A[(long)am * LAT_ + kb + (lchunk ^ csw) * 8],        &Ash[ra * 32 + lchunk * 8]);
      glds16(&WpE[(long)(n0 + ra) * LAT_ + kb + (lchunk ^ csw) * 8], &Bsh[ra * 32 + lchunk * 8]);
    }
    __syncthreads();
    short8 af[4], bq[4];
    #pragma unroll
    for (int i = 0; i < 4; ++i) af[i] = *(const short8*)&Ash[(mh + i * 16 + frow) * 32 + sA];
    #pragma unroll
    for (int j = 0; j < 4; ++j) bq[j] = *(const short8*)&Bsh[(nh + j * 16 + frow) * 32 + sA];
    #pragma unroll
    for (int i = 0; i < 4; ++i)
      #pragma unroll
      for (int j = 0; j < 4; ++j)
        acc[i][j] = __builtin_amdgcn_mfma_f32_16x16x32_bf16(af[i], bq[j], acc[i][j], 0, 0, 0);
    __syncthreads();
  }
  #pragma unroll
  for (int i = 0; i < 4; ++i) {
    #pragma unroll
    for (int r = 0; r < 4; ++r) {
      int mu = m0 + mh + i * 16 + (lane >> 4) * 4 + r;
      if (mu >= 528) continue;
      int pr_ = PAIR[mu];
      int ii = pr_ >> 5, jj = pr_ & 31;
      #pragma unroll
      for (int j = 0; j < 4; ++j) {
        int n = n0 + nh + j * 16 + (lane & 15);
        int nt = n >> 9, nn2 = n & 511;
        float base = acc[i][j][r] + bnp[2048 + n];
        float sc = bnp[nt * 1024 + nn2], sh = bnp[nt * 1024 + 512 + nn2];
        float Ai_i = A4[((long)b * 32 + ii) * 2048 + nt * 1024 + nn2];
        float Aj_j = A4[((long)b * 32 + jj) * 2048 + nt * 1024 + 512 + nn2];
        long e1 = ((long)b * 1024 + ii * 32 + jj) * 1024 + n;
        float v1 = base + Ai_i + Aj_j;
        XFh[e1] = f2b(v1);
        DH[e1]  = f2b(fmaxf(fmaf(v1, sc, sh), 0.f));
        if (ii != jj) {
          float Ai_j = A4[((long)b * 32 + jj) * 2048 + nt * 1024 + nn2];
          float Aj_i = A4[((long)b * 32 + ii) * 2048 + nt * 1024 + 512 + nn2];
          long e2 = ((long)b * 1024 + jj * 32 + ii) * 1024 + n;
          float v2 = base + Ai_j + Aj_i;
          XFh[e2] = f2b(v2);
          DH[e2]  = f2b(fmaxf(fmaf(v2, sc, sh), 0.f));
        }
      }
    }
  }
}

// ---------------- chorus-p only, swizzled ----------------
__global__ __launch_bounds__(256) void chorus_k(
    const bf16* __restrict__ DH, const bf16* __restrict__ pcw16,
    const float* __restrict__ bnp, const bf16* __restrict__ XFh,
    bf16* __restrict__ Yp16) {
  int b = blockIdx.z;
  int m0 = blockIdx.x * 128, n0 = blockIdx.y * 128;
  const bf16* A = DH + (long)b * 1024 * 1024 + 512;
  __shared__ bf16 Ash[128 * 32];
  __shared__ bf16 Bsh[128 * 32];
  int t = threadIdx.x, w = t >> 6, lane = t & 63;
  int mh = (w & 1) * 64, nh = (w >> 1) * 64;
  int frow = lane & 15, cf = lane >> 4;
  int lrow = lane >> 2, lchunk = lane & 3;
  int csw = (lrow >> 1) & 3;
  int sA = (cf ^ ((frow >> 1) & 3)) * 8;
  f32x4 acc[4][4] = {};
  for (int kb = 0; kb < 512; kb += 32) {
    #pragma unroll
    for (int q = 0; q < 2; ++q) {
      int ra = q * 64 + w * 16 + lrow;
      glds16(&A[(long)(m0 + ra) * 1024 + kb + (lchunk ^ csw) * 8],     &Ash[ra * 32 + lchunk * 8]);
      glds16(&pcw16[(long)(n0 + ra) * 512 + kb + (lchunk ^ csw) * 8],  &Bsh[ra * 32 + lchunk * 8]);
    }
    __syncthreads();
    short8 af[4], bq[4];
    #pragma unroll
    for (int i = 0; i < 4; ++i) af[i] = *(const short8*)&Ash[(mh + i * 16 + frow) * 32 + sA];
    #pragma unroll
    for (int j = 0; j < 4; ++j) bq[j] = *(const short8*)&Bsh[(nh + j * 16 + frow) * 32 + sA];
    #pragma unroll
    for (int i = 0; i < 4; ++i)
      #pragma unroll
      for (int j = 0; j < 4; ++j)
        acc[i][j] = __builtin_amdgcn_mfma_f32_16x16x32_bf16(af[i], bq[j], acc[i][j], 0, 0, 0);
    __syncthreads();
  }
  #pragma unroll
  for (int i = 0; i < 4; ++i)
    #pragma unroll
    for (int j = 0; j < 4; ++j)
      #pragma unroll
      for (int r = 0; r < 4; ++r) {
        int m = m0 + mh + i * 16 + (lane >> 4) * 4 + r;
        int n = n0 + nh + j * 16 + (lane & 15);
        float v = acc[i][j][r] + bnp[3584 + n]
                + b2f(XFh[((long)b * 1024 + m) * 1024 + 512 + n]);
        Yp16[((long)b * 1024 + m) * 512 + n] = f2b(v);
      }
}

// ---------------- outro: PR[b][1024][64] ----------------
__global__ __launch_bounds__(256) void outro_k(
    const bf16* __restrict__ Yp16, const bf16* __restrict__ pow16,
    const float* __restrict__ p_ob, float* __restrict__ PR) {
  int b = blockIdx.z;
  const bf16* Ab = Yp16 + (long)b * 1024 * 512;
  int m0 = blockIdx.x * 64;
  __shared__ bf16 Ash[64][40];
  __shared__ bf16 Bsh[64][40];
  int t = threadIdx.x, w = t >> 6, lane = t & 63;
  int mq = w * 16;
  int frow = lane & 15, fko = (lane >> 4) * 8;
  f32x4 acc[4] = {};
  for (int kb = 0; kb < 512; kb += 32) {
    { int r = t >> 2, ko = (t & 3) * 8;
      *(uint4*)&Ash[r][ko] = *(const uint4*)&Ab[(long)(m0 + r) * 512 + kb + ko];
      *(uint4*)&Bsh[r][ko] = *(const uint4*)&pow16[(long)r * 512 + kb + ko]; }
    __syncthreads();
    short8 af = *(const short8*)&Ash[mq + frow][fko];
    #pragma unroll
    for (int j = 0; j < 4; ++j) {
      short8 bq = *(const short8*)&Bsh[j * 16 + frow][fko];
      acc[j] = __builtin_amdgcn_mfma_f32_16x16x32_bf16(af, bq, acc[j], 0, 0, 0);
    }
    __syncthreads();
  }
  #pragma unroll
  for (int j = 0; j < 4; ++j)
    #pragma unroll
    for (int r = 0; r < 4; ++r) {
      int m = m0 + mq + (lane >> 4) * 4 + r;
      int n = j * 16 + (lane & 15);
      PR[((long)b * 1024 + m) * 64 + n] = acc[j][r] + p_ob[n];
    }
}

// ---------------- final: gate (folded chorus-g) + normalize + mask ----------------
__global__ __launch_bounds__(256) void final3_k(
    const bf16* __restrict__ XFh, const bf16* __restrict__ DH, const float* __restrict__ PR,
    const float* __restrict__ u, const float* __restrict__ g_ow,
    const float* __restrict__ g_cb, const float* __restrict__ g_ob,
    const int* __restrict__ n, float* __restrict__ out) {
  int gw = blockIdx.x * 4 + (threadIdx.x >> 6);
  int lane = threadIdx.x & 63;
  int b = gw >> 10, ij = gw & 1023;
  const bf16* xr = XFh + ((long)b * 1024 + ij) * 1024;
  const bf16* dr = DH  + ((long)b * 1024 + ij) * 1024;
  float gl = 0.f;
  #pragma unroll
  for (int q = 0; q < 8; ++q) {
    int nn = q * 64 + lane;
    float go = g_ow[nn];
    gl = fmaf(go, b2f(xr[nn]) + g_cb[nn], gl);      // g_ow·X + c0 fused
    gl = fmaf(u[nn], b2f(dr[nn]), gl);              // u·relu(bn(X))
  }
  #pragma unroll
  for (int off = 32; off; off >>= 1) gl += __shfl_down(gl, off);
  gl = __shfl(gl, 0) + g_ob[0];
  float gate = 1.f / (1.f + expf(-gl));
  int i = ij >> 5, j = ij & 31, nb = n[b];
  float maskv = (i < nb && j < nb) ? 1.f : 0.f;
  float v = PR[((long)b * 1024 + ij) * 64 + lane];
  float ss = v * v;
  #pragma unroll
  for (int off = 32; off; off >>= 1) ss += __shfl_down(ss, off);
  ss = __shfl(ss, 0);
  float scale = gate * maskv / fmaxf(sqrtf(ss), 1e-12f);
  out[((long)b * 64 + lane) * 1024 + ij] = v * scale;
}

extern "C" void kernel_launch(void* const* d_in, const int* in_sizes, int n_in,
                              void* d_out, int out_size, void* d_ws, size_t ws_size,
                              hipStream_t stream) {
  const float* f0 = (const float*)d_in[0];
  const float* f1 = (const float*)d_in[1];
  const float* f2 = (const float*)d_in[2];
  const float* f3 = (const float*)d_in[3];
  const float* f4 = (const float*)d_in[4];
  const float* f5 = (const float*)d_in[5];
  const float* P  = (const float*)d_in[6];
  const int*   n  = (const int*)d_in[7];
  const float *g_iw=(const float*)d_in[8],  *g_ib=(const float*)d_in[9],
              *g_bg=(const float*)d_in[10], *g_bb=(const float*)d_in[11],
              *g_bm=(const float*)d_in[12], *g_bv=(const float*)d_in[13],
              *g_cw=(const float*)d_in[14], *g_cb=(const float*)d_in[15],
              *g_ow=(const float*)d_in[16], *g_ob=(const float*)d_in[17];
  const float *p_iw=(const float*)d_in[18], *p_ib=(const float*)d_in[19],
              *p_bg=(const float*)d_in[20], *p_bb=(const float*)d_in[21],
              *p_bm=(const float*)d_in[22], *p_bv=(const float*)d_in[23],
              *p_cw=(const float*)d_in[24], *p_cb=(const float*)d_in[25],
              *p_ow=(const float*)d_in[26], *p_ob=(const float*)d_in[27];
  float* out = (float*)d_out;
  char* wsb = (char*)d_ws;

  // workspace (byte offsets)
  bf16*  Sb    = (bf16*)(wsb + 0);            // 8*560*1536*2 = 13,762,560
  bf16*  Wp    = (bf16*)(wsb + 13762560);     // 9,437,184 -> 23,199,744
  bf16*  pcw16 = (bf16*)(wsb + 23199744);     // 524,288   -> 23,724,032
  bf16*  pow16 = (bf16*)(wsb + 23724032);     // 65,536    -> 23,789,568
  bf16*  T5    = (bf16*)(wsb + 23789568);     // 8,192     -> 23,797,760
  float* bnp   = (float*)(wsb + 23797760);    // 16,384    -> 23,814,144
  int*   PAIR  = (int*)(wsb + 23814144);      // 2,112     -> 23,816,256
  float* u     = (float*)(wsb + 23816256);    // 2,048     -> 23,818,304
  float* A4    = (float*)(wsb + 23818304);    // 2,097,152 -> 25,915,456
  bf16*  XFh   = (bf16*)(wsb + 25915456);     // 16,777,216-> 42,692,672
  bf16*  DH    = (bf16*)(wsb + 42692672);     // 16,777,216-> 59,469,888
  bf16*  Yp16  = (bf16*)(wsb + 59469888);     // 8,388,608 -> 67,858,496
  float* PR    = (float*)(wsb + 67858496);    // 2,097,152 -> 69,955,648
  // T0..T4 overlay XFh/DH (dead until edge_k)
  bf16*  T0 = (bf16*)(wsb + 25915456);
  bf16*  T1 = (bf16*)(wsb + 42692672);
  bf16*  T2 = (bf16*)(wsb + 46886976);
  bf16*  T3 = (bf16*)(wsb + 48984128);
  bf16*  T4 = (bf16*)(wsb + 50032704);
  bf16*  WpE = Wp + (long)2048 * LAT_;

  packA_k<<<dim3(3072, 6), 256, 0, stream>>>(g_iw, p_iw, Wp);
  packB_k<<<dim3(1024, 2), 256, 0, stream>>>(p_cw, p_ow, f5,
      g_bg, g_bb, g_bm, g_bv, p_bg, p_bb, p_bm, p_bv, g_ib, p_ib, p_cb,
      g_ow, g_cw, pcw16, pow16, T5, bnp, PAIR, u);
  transpose_all_k<<<dim3(376, 8), 256, 0, stream>>>(f0, f1, f2, f3, f4, T0, T1, T2, T3, T4);
  sample4_k<<<dim3(35, 8), 256, 0, stream>>>(T0, T1, T2, T3, T4, T5, P, PAIR, Sb);
  nodegemm_k<<<dim3(32, 8), 256, 0, stream>>>(Sb, Wp, A4);
  edge_k<<<dim3(5, 8, 8), 256, 0, stream>>>(Sb, WpE, bnp, A4, PAIR, XFh, DH);
  chorus_k<<<dim3(8, 4, 8), 256, 0, stream>>>(DH, pcw16, bnp, XFh, Yp16);
  outro_k<<<dim3(16, 1, 8), 256, 0, stream>>>(Yp16, pow16, p_ob, PR);
  final3_k<<<dim3(2048), 256, 0, stream>>>(XFh, DH, PR, u, g_ow, g_cb, g_ob, n, out);
}

// Round 7
// 265.259 us; speedup vs baseline: 1.2715x; 1.2715x over previous
//
#include <hip/hip_runtime.h>
#include <hip/hip_bf16.h>

using bf16 = __hip_bfloat16;
using short8 = __attribute__((ext_vector_type(8))) short;
using f32x4  = __attribute__((ext_vector_type(4))) float;
typedef unsigned int u32;

#define LAT_ 1536

__device__ __forceinline__ void glds16(const bf16* g, bf16* l) {
  __builtin_amdgcn_global_load_lds(
      (const __attribute__((address_space(1))) void*)g,
      (__attribute__((address_space(3))) void*)l, 16, 0, 0);
}
__device__ __forceinline__ float b2f(bf16 x) { return __bfloat162float(x); }
__device__ __forceinline__ bf16 f2b(float x) { return __float2bfloat16(x); }

// ---------------- NCHW fp32 -> NHWC bf16 tile ----------------
template<int C, int W>
__device__ __forceinline__ void trans_tile(const float* __restrict__ src, bf16* __restrict__ dst,
                                           int b, int hw0, int c0, bf16 (*tile)[72], int t) {
  constexpr int HW = W * W;
  {
    int cl = t >> 2, h0 = (t & 3) * 16;
    const float* sp = src + (long)(b * C + c0 + cl) * HW + hw0 + h0;
    #pragma unroll
    for (int k = 0; k < 16; k += 4) {
      float4 v = *(const float4*)(sp + k);
      tile[h0 + k + 0][cl] = f2b(v.x);
      tile[h0 + k + 1][cl] = f2b(v.y);
      tile[h0 + k + 2][cl] = f2b(v.z);
      tile[h0 + k + 3][cl] = f2b(v.w);
    }
  }
  __syncthreads();
  {
    int hwl = t >> 2, cc = (t & 3) * 16;
    bf16* dp = dst + ((long)b * HW + hw0 + hwl) * C + c0 + cc;
    #pragma unroll
    for (int k = 0; k < 16; k += 2) {
      __hip_bfloat162 pr;
      pr.x = tile[hwl][cc + k];
      pr.y = tile[hwl][cc + k + 1];
      *(__hip_bfloat162*)(dp + k) = pr;
    }
  }
}

// ---------------- fused prep: packA | pcw | pow | T5 | bn | u | transposes ----------------
// block ranges: [0,18432) packA, [18432,19456) pcw, [19456,19584) pow,
// [19584,19600) T5, [19600,19602) bn, [19602,19610) u, [19610,22618) transpose
__global__ __launch_bounds__(256) void prep_k(
    const float* __restrict__ g_iw, const float* __restrict__ p_iw,
    const float* __restrict__ p_cw, const float* __restrict__ p_ow, const float* __restrict__ f5,
    const float* __restrict__ g_bg, const float* __restrict__ g_bb, const float* __restrict__ g_bm,
    const float* __restrict__ g_bv, const float* __restrict__ p_bg, const float* __restrict__ p_bb,
    const float* __restrict__ p_bm, const float* __restrict__ p_bv,
    const float* __restrict__ g_ib, const float* __restrict__ p_ib, const float* __restrict__ p_cb,
    const float* __restrict__ g_ow, const float* __restrict__ g_cw,
    const float* __restrict__ f0, const float* __restrict__ f1, const float* __restrict__ f2,
    const float* __restrict__ f3, const float* __restrict__ f4,
    bf16* __restrict__ Wp, bf16* __restrict__ pcw16, bf16* __restrict__ pow16,
    bf16* __restrict__ T5, float* __restrict__ bnp, float* __restrict__ u,
    bf16* __restrict__ T0, bf16* __restrict__ T1, bf16* __restrict__ T2,
    bf16* __restrict__ T3, bf16* __restrict__ T4) {
  __shared__ bf16 tile[64][72];
  __shared__ float ured[4][64];
  int B = blockIdx.x, t = threadIdx.x;
  if (B < 18432) {                                    // packA
    int seg = B / 3072;
    int idx = (B % 3072) * 256 + t;
    if (idx < 512 * 1536) {
      int r = idx / 1536, c = idx % 1536;
      const float* src; int co;
      switch (seg) {
        case 0: src = g_iw; co = 0;    break;
        case 1: src = g_iw; co = 1536; break;
        case 2: src = p_iw; co = 0;    break;
        case 3: src = p_iw; co = 1536; break;
        case 4: src = g_iw; co = 3072; break;
        default: src = p_iw; co = 3072; break;
      }
      Wp[(long)seg * 512 * 1536 + idx] = f2b(src[(long)r * 4608 + co + c]);
    }
    return;
  }
  if (B < 19456) { int idx = (B - 18432) * 256 + t; pcw16[idx] = f2b(p_cw[idx]); return; }
  if (B < 19584) { int idx = (B - 19456) * 256 + t; pow16[idx] = f2b(p_ow[idx]); return; }
  if (B < 19600) { int idx = (B - 19584) * 256 + t; T5[idx] = f2b(f5[idx]); return; }
  if (B < 19602) {                                    // bn consts
    int k = (B - 19600) * 256 + t;
    if (k < 512) {
      float sg = g_bg[k] / sqrtf(g_bv[k] + 1e-5f);
      bnp[k] = sg; bnp[512 + k] = g_bb[k] - g_bm[k] * sg;
      float sp = p_bg[k] / sqrtf(p_bv[k] + 1e-5f);
      bnp[1024 + k] = sp; bnp[1536 + k] = p_bb[k] - p_bm[k] * sp;
      bnp[2048 + k] = g_ib[k]; bnp[2560 + k] = p_ib[k];
      bnp[3584 + k] = p_cb[k];
    }
    return;
  }
  if (B < 19610) {                                    // u[k] = sum_o g_ow[o]*g_cw[o*512+k]
    int k0 = (B - 19602) * 64;
    int kk = t & 63, part = t >> 6;
    int k = k0 + kk;
    float s = 0.f;
    for (int o = part * 128; o < part * 128 + 128; ++o)
      s = fmaf(g_ow[o], g_cw[o * 512 + k], s);
    ured[part][kk] = s;
    __syncthreads();
    if (part == 0) u[k] = ured[0][kk] + ured[1][kk] + ured[2][kk] + ured[3][kk];
    return;
  }
  {                                                   // transposes
    int q = B - 19610;                                // 0..3007
    int b = q / 376, tt = q % 376;
    if (tt < 256)      trans_tile<64, 128>(f0, T0, b, tt * 64, 0, tile, t);
    else if (tt < 320) trans_tile<64, 64 >(f1, T1, b, (tt - 256) * 64, 0, tile, t);
    else if (tt < 352) { int z = tt - 320; trans_tile<128, 32>(f2, T2, b, (z & 15) * 64, (z >> 4) * 64, tile, t); }
    else if (tt < 368) { int z = tt - 352; trans_tile<256, 16>(f3, T3, b, (z & 3) * 64, (z >> 2) * 64, tile, t); }
    else               { int z = tt - 368; trans_tile<512, 8 >(f4, T4, b, 0, z * 64, tile, t); }
  }
}

// ---------------- sampling: Sb[b][m=1056][k=1536], level-parallel ----------------
__device__ __forceinline__ float blo(u32 r) { return __uint_as_float(r << 16); }
__device__ __forceinline__ float bhi(u32 r) { return __uint_as_float(r & 0xffff0000u); }

template<int C, int W>
__device__ __forceinline__ void proc2(const bf16* __restrict__ T, int b,
    const float* MX, const float* MY, bf16* __restrict__ Sb, int koff, int t) {
  constexpr int C2 = C / 2, HW = W * W;
  const bf16* Tb = T + (long)b * HW * C;
  for (int idx = t; idx < 16 * C2; idx += 256) {
    int q = idx / C2, c2 = idx % C2;
    float x = MX[q], y = MY[q];
    float fx = fminf(fmaxf(x * ((float)W / 256.f) - 0.5f, 0.f), (float)(W - 1));
    float fy = fminf(fmaxf(y * ((float)W / 256.f) - 0.5f, 0.f), (float)(W - 1));
    float x0f = floorf(fx), y0f = floorf(fy);
    float wx = fx - x0f, wy = fy - y0f;
    int x0 = (int)x0f, y0 = (int)y0f;
    int x1 = min(x0 + 1, W - 1), y1 = min(y0 + 1, W - 1);
    u32 r00 = *(const u32*)&Tb[(y0 * W + x0) * C + 2 * c2];
    u32 r01 = *(const u32*)&Tb[(y0 * W + x1) * C + 2 * c2];
    u32 r10 = *(const u32*)&Tb[(y1 * W + x0) * C + 2 * c2];
    u32 r11 = *(const u32*)&Tb[(y1 * W + x1) * C + 2 * c2];
    float w00 = (1.f - wx) * (1.f - wy), w01 = wx * (1.f - wy);
    float w10 = (1.f - wx) * wy,        w11 = wx * wy;
    float vlo = blo(r00) * w00 + blo(r01) * w01 + blo(r10) * w10 + blo(r11) * w11;
    float vhi = bhi(r00) * w00 + bhi(r01) * w01 + bhi(r10) * w10 + bhi(r11) * w11;
    __hip_bfloat162 pr;
    pr.x = f2b(vlo); pr.y = f2b(vhi);
    *(__hip_bfloat162*)&Sb[(long)q * LAT_ + koff + 2 * c2] = pr;
  }
}

__global__ __launch_bounds__(256) void sample5_k(
    const bf16* __restrict__ T0, const bf16* __restrict__ T1, const bf16* __restrict__ T2,
    const bf16* __restrict__ T3, const bf16* __restrict__ T4, const bf16* __restrict__ T5,
    const float* __restrict__ P, bf16* __restrict__ Sball) {
  int b = blockIdx.z, p0 = blockIdx.x * 16, lvl = blockIdx.y, t = threadIdx.x;
  __shared__ float Px[32], Py[32], MX[16], MY[16];
  if (t < 32) { Px[t] = P[(b * 32 + t) * 2]; Py[t] = P[(b * 32 + t) * 2 + 1]; }
  __syncthreads();
  if (t < 16) {
    int m = p0 + t;
    float x, y;
    if (m < 32) { x = Px[m]; y = Py[m]; }
    else { int ij = m - 32, i = ij >> 5, j = ij & 31;
           x = 0.5f * (Px[i] + Px[j]); y = 0.5f * (Py[i] + Py[j]); }
    MX[t] = x; MY[t] = y;
  }
  __syncthreads();
  bf16* Sb = Sball + ((long)b * 1056 + p0) * LAT_;
  switch (lvl) {
    case 0: proc2<64, 128>(T0, b, MX, MY, Sb, 0,    t); break;
    case 1: proc2<64, 64 >(T1, b, MX, MY, Sb, 64,   t); break;
    case 2: proc2<128, 32>(T2, b, MX, MY, Sb, 128,  t); break;
    case 3: proc2<256, 16>(T3, b, MX, MY, Sb, 256,  t); break;
    case 4: proc2<512, 8 >(T4, b, MX, MY, Sb, 512,  t); break;
    default:
      for (int idx = t; idx < 16 * 256; idx += 256) {
        int q = idx >> 8, c2 = idx & 255;
        *(__hip_bfloat162*)&Sb[(long)q * LAT_ + 1024 + 2 * c2] =
            *(const __hip_bfloat162*)&T5[b * 512 + 2 * c2];
      }
  }
}

// ---------------- node GEMM: A4[b][32][2048] ----------------
__global__ __launch_bounds__(256) void nodegemm_k(
    const bf16* __restrict__ Sball, const bf16* __restrict__ Wp, float* __restrict__ A4) {
  int b = blockIdx.y;
  int n0 = blockIdx.x * 64;
  int t = threadIdx.x, w = t >> 6, lane = t & 63;
  int nn = n0 + w * 16;
  int frow = lane & 15, fko = (lane >> 4) * 8;
  const bf16* Ab = Sball + (long)b * 1056 * LAT_;
  f32x4 acc[2] = {};
  for (int kb = 0; kb < LAT_; kb += 32) {
    short8 bq = *(const short8*)&Wp[(long)(nn + frow) * LAT_ + kb + fko];
    #pragma unroll
    for (int i = 0; i < 2; ++i) {
      short8 aq = *(const short8*)&Ab[(long)(i * 16 + frow) * LAT_ + kb + fko];
      acc[i] = __builtin_amdgcn_mfma_f32_16x16x32_bf16(aq, bq, acc[i], 0, 0, 0);
    }
  }
  #pragma unroll
  for (int i = 0; i < 2; ++i)
    #pragma unroll
    for (int r = 0; r < 4; ++r) {
      int m = i * 16 + (lane >> 4) * 4 + r;
      int n = nn + (lane & 15);
      A4[(long)b * 65536 + m * 2048 + n] = acc[i][r];
    }
}

// ---------------- edge GEMM: M=1024, N=1024 (g|p), K=1536, swizzled LDS ----------------
__global__ __launch_bounds__(256) void edge_k(
    const bf16* __restrict__ Sball, const bf16* __restrict__ WpE,
    const float* __restrict__ bnp, const float* __restrict__ A4,
    bf16* __restrict__ XFh, bf16* __restrict__ DH) {
  int b = blockIdx.z;
  int m0 = blockIdx.x * 128, n0 = blockIdx.y * 128;
  const bf16* A = Sball + (long)b * 1056 * LAT_ + 32 * LAT_;
  __shared__ bf16 Ash[128 * 32];
  __shared__ bf16 Bsh[128 * 32];
  int t = threadIdx.x, w = t >> 6, lane = t & 63;
  int mh = (w & 1) * 64, nh = (w >> 1) * 64;
  int frow = lane & 15, cf = lane >> 4;
  int lrow = lane >> 2, lchunk = lane & 3;
  int csw = (lrow >> 1) & 3;
  int sA = (cf ^ ((frow >> 1) & 3)) * 8;
  f32x4 acc[4][4] = {};
  for (int kb = 0; kb < LAT_; kb += 32) {
    #pragma unroll
    for (int q = 0; q < 2; ++q) {
      int ra = q * 64 + w * 16 + lrow;
      glds16(&A[(long)(m0 + ra) * LAT_ + kb + (lchunk ^ csw) * 8],   &Ash[ra * 32 + lchunk * 8]);
      glds16(&WpE[(long)(n0 + ra) * LAT_ + kb + (lchunk ^ csw) * 8], &Bsh[ra * 32 + lchunk * 8]);
    }
    __syncthreads();
    short8 af[4], bq[4];
    #pragma unroll
    for (int i = 0; i < 4; ++i) af[i] = *(const short8*)&Ash[(mh + i * 16 + frow) * 32 + sA];
    #pragma unroll
    for (int j = 0; j < 4; ++j) bq[j] = *(const short8*)&Bsh[(nh + j * 16 + frow) * 32 + sA];
    #pragma unroll
    for (int i = 0; i < 4; ++i)
      #pragma unroll
      for (int j = 0; j < 4; ++j)
        acc[i][j] = __builtin_amdgcn_mfma_f32_16x16x32_bf16(af[i], bq[j], acc[i][j], 0, 0, 0);
    __syncthreads();
  }
  #pragma unroll
  for (int i = 0; i < 4; ++i) {
    #pragma unroll
    for (int j = 0; j < 4; ++j) {
      #pragma unroll
      for (int r = 0; r < 4; ++r) {
        int m = m0 + mh + i * 16 + (lane >> 4) * 4 + r;
        int n = n0 + nh + j * 16 + (lane & 15);
        int nt = n >> 9, nn2 = n & 511;
        float v = acc[i][j][r] + bnp[2048 + n]
                + A4[((long)b * 32 + (m >> 5)) * 2048 + nt * 1024 + nn2]
                + A4[((long)b * 32 + (m & 31)) * 2048 + nt * 1024 + 512 + nn2];
        XFh[((long)b * 1024 + m) * 1024 + n] = f2b(v);
        float d = fmaxf(fmaf(v, bnp[nt * 1024 + nn2], bnp[nt * 1024 + 512 + nn2]), 0.f);
        DH[((long)b * 1024 + m) * 1024 + n] = f2b(d);
      }
    }
  }
}

// ---------------- chorus-p, swizzled ----------------
__global__ __launch_bounds__(256) void chorus_k(
    const bf16* __restrict__ DH, const bf16* __restrict__ pcw16,
    const float* __restrict__ bnp, const bf16* __restrict__ XFh,
    bf16* __restrict__ Yp16) {
  int b = blockIdx.z;
  int m0 = blockIdx.x * 128, n0 = blockIdx.y * 128;
  const bf16* A = DH + (long)b * 1024 * 1024 + 512;
  __shared__ bf16 Ash[128 * 32];
  __shared__ bf16 Bsh[128 * 32];
  int t = threadIdx.x, w = t >> 6, lane = t & 63;
  int mh = (w & 1) * 64, nh = (w >> 1) * 64;
  int frow = lane & 15, cf = lane >> 4;
  int lrow = lane >> 2, lchunk = lane & 3;
  int csw = (lrow >> 1) & 3;
  int sA = (cf ^ ((frow >> 1) & 3)) * 8;
  f32x4 acc[4][4] = {};
  for (int kb = 0; kb < 512; kb += 32) {
    #pragma unroll
    for (int q = 0; q < 2; ++q) {
      int ra = q * 64 + w * 16 + lrow;
      glds16(&A[(long)(m0 + ra) * 1024 + kb + (lchunk ^ csw) * 8],    &Ash[ra * 32 + lchunk * 8]);
      glds16(&pcw16[(long)(n0 + ra) * 512 + kb + (lchunk ^ csw) * 8], &Bsh[ra * 32 + lchunk * 8]);
    }
    __syncthreads();
    short8 af[4], bq[4];
    #pragma unroll
    for (int i = 0; i < 4; ++i) af[i] = *(const short8*)&Ash[(mh + i * 16 + frow) * 32 + sA];
    #pragma unroll
    for (int j = 0; j < 4; ++j) bq[j] = *(const short8*)&Bsh[(nh + j * 16 + frow) * 32 + sA];
    #pragma unroll
    for (int i = 0; i < 4; ++i)
      #pragma unroll
      for (int j = 0; j < 4; ++j)
        acc[i][j] = __builtin_amdgcn_mfma_f32_16x16x32_bf16(af[i], bq[j], acc[i][j], 0, 0, 0);
    __syncthreads();
  }
  #pragma unroll
  for (int i = 0; i < 4; ++i)
    #pragma unroll
    for (int j = 0; j < 4; ++j)
      #pragma unroll
      for (int r = 0; r < 4; ++r) {
        int m = m0 + mh + i * 16 + (lane >> 4) * 4 + r;
        int n = n0 + nh + j * 16 + (lane & 15);
        float v = acc[i][j][r] + bnp[3584 + n]
                + b2f(XFh[((long)b * 1024 + m) * 1024 + 512 + n]);
        Yp16[((long)b * 1024 + m) * 512 + n] = f2b(v);
      }
}

// ---------------- outro: PR[b][1024][64] ----------------
__global__ __launch_bounds__(256) void outro_k(
    const bf16* __restrict__ Yp16, const bf16* __restrict__ pow16,
    const float* __restrict__ p_ob, float* __restrict__ PR) {
  int b = blockIdx.z;
  const bf16* Ab = Yp16 + (long)b * 1024 * 512;
  int m0 = blockIdx.x * 64;
  __shared__ bf16 Ash[64][40];
  __shared__ bf16 Bsh[64][40];
  int t = threadIdx.x, w = t >> 6, lane = t & 63;
  int mq = w * 16;
  int frow = lane & 15, fko = (lane >> 4) * 8;
  f32x4 acc[4] = {};
  for (int kb = 0; kb < 512; kb += 32) {
    { int r = t >> 2, ko = (t & 3) * 8;
      *(uint4*)&Ash[r][ko] = *(const uint4*)&Ab[(long)(m0 + r) * 512 + kb + ko];
      *(uint4*)&Bsh[r][ko] = *(const uint4*)&pow16[(long)r * 512 + kb + ko]; }
    __syncthreads();
    short8 af = *(const short8*)&Ash[mq + frow][fko];
    #pragma unroll
    for (int j = 0; j < 4; ++j) {
      short8 bq = *(const short8*)&Bsh[j * 16 + frow][fko];
      acc[j] = __builtin_amdgcn_mfma_f32_16x16x32_bf16(af, bq, acc[j], 0, 0, 0);
    }
    __syncthreads();
  }
  #pragma unroll
  for (int j = 0; j < 4; ++j)
    #pragma unroll
    for (int r = 0; r < 4; ++r) {
      int m = m0 + mq + (lane >> 4) * 4 + r;
      int n = j * 16 + (lane & 15);
      PR[((long)b * 1024 + m) * 64 + n] = acc[j][r] + p_ob[n];
    }
}

// ---------------- final: gate (folded chorus-g) + normalize + mask ----------------
__global__ __launch_bounds__(256) void final3_k(
    const bf16* __restrict__ XFh, const bf16* __restrict__ DH, const float* __restrict__ PR,
    const float* __restrict__ u, const float* __restrict__ g_ow,
    const float* __restrict__ g_cb, const float* __restrict__ g_ob,
    const int* __restrict__ n, float* __restrict__ out) {
  int gw = blockIdx.x * 4 + (threadIdx.x >> 6);
  int lane = threadIdx.x & 63;
  int b = gw >> 10, ij = gw & 1023;
  const bf16* xr = XFh + ((long)b * 1024 + ij) * 1024;
  const bf16* dr = DH  + ((long)b * 1024 + ij) * 1024;
  float gl = 0.f;
  #pragma unroll
  for (int q = 0; q < 8; ++q) {
    int nn = q * 64 + lane;
    gl = fmaf(g_ow[nn], b2f(xr[nn]) + g_cb[nn], gl);
    gl = fmaf(u[nn], b2f(dr[nn]), gl);
  }
  #pragma unroll
  for (int off = 32; off; off >>= 1) gl += __shfl_down(gl, off);
  gl = __shfl(gl, 0) + g_ob[0];
  float gate = 1.f / (1.f + expf(-gl));
  int i = ij >> 5, j = ij & 31, nb = n[b];
  float maskv = (i < nb && j < nb) ? 1.f : 0.f;
  float v = PR[((long)b * 1024 + ij) * 64 + lane];
  float ss = v * v;
  #pragma unroll
  for (int off = 32; off; off >>= 1) ss += __shfl_down(ss, off);
  ss = __shfl(ss, 0);
  float scale = gate * maskv / fmaxf(sqrtf(ss), 1e-12f);
  out[((long)b * 64 + lane) * 1024 + ij] = v * scale;
}

extern "C" void kernel_launch(void* const* d_in, const int* in_sizes, int n_in,
                              void* d_out, int out_size, void* d_ws, size_t ws_size,
                              hipStream_t stream) {
  const float* f0 = (const float*)d_in[0];
  const float* f1 = (const float*)d_in[1];
  const float* f2 = (const float*)d_in[2];
  const float* f3 = (const float*)d_in[3];
  const float* f4 = (const float*)d_in[4];
  const float* f5 = (const float*)d_in[5];
  const float* P  = (const float*)d_in[6];
  const int*   n  = (const int*)d_in[7];
  const float *g_iw=(const float*)d_in[8],  *g_ib=(const float*)d_in[9],
              *g_bg=(const float*)d_in[10], *g_bb=(const float*)d_in[11],
              *g_bm=(const float*)d_in[12], *g_bv=(const float*)d_in[13],
              *g_cw=(const float*)d_in[14], *g_cb=(const float*)d_in[15],
              *g_ow=(const float*)d_in[16], *g_ob=(const float*)d_in[17];
  const float *p_iw=(const float*)d_in[18], *p_ib=(const float*)d_in[19],
              *p_bg=(const float*)d_in[20], *p_bb=(const float*)d_in[21],
              *p_bm=(const float*)d_in[22], *p_bv=(const float*)d_in[23],
              *p_cw=(const float*)d_in[24], *p_cb=(const float*)d_in[25],
              *p_ow=(const float*)d_in[26], *p_ob=(const float*)d_in[27];
  float* out = (float*)d_out;
  char* wsb = (char*)d_ws;

  // workspace (byte offsets)
  bf16*  Sb    = (bf16*)(wsb + 0);            // 8*1056*1536*2 = 25,952,256
  bf16*  Wp    = (bf16*)(wsb + 25952256);     // 9,437,184  -> 35,389,440
  bf16*  pcw16 = (bf16*)(wsb + 35389440);     // 524,288    -> 35,913,728
  bf16*  pow16 = (bf16*)(wsb + 35913728);     // 65,536     -> 35,979,264
  bf16*  T5    = (bf16*)(wsb + 35979264);     // 8,192      -> 35,987,456
  float* bnp   = (float*)(wsb + 35987456);    // 16,384     -> 36,003,840
  float* u     = (float*)(wsb + 36003840);    // 2,048      -> 36,005,888
  float* A4    = (float*)(wsb + 36005888);    // 2,097,152  -> 38,103,040
  bf16*  XFh   = (bf16*)(wsb + 38103040);     // 16,777,216 -> 54,880,256
  bf16*  DH    = (bf16*)(wsb + 54880256);     // 16,777,216 -> 71,657,472
  bf16*  Yp16  = (bf16*)(wsb + 71657472);     // 8,388,608  -> 80,046,080
  float* PR    = (float*)(wsb + 80046080);    // 2,097,152  -> 82,143,232
  // T0..T4 overlay XFh/DH (dead until edge_k)
  bf16*  T0 = (bf16*)(wsb + 38103040);        // 16,777,216 (over XFh)
  bf16*  T1 = (bf16*)(wsb + 54880256);        // 4,194,304  (over DH)
  bf16*  T2 = (bf16*)(wsb + 59074560);        // 2,097,152
  bf16*  T3 = (bf16*)(wsb + 61171712);        // 1,048,576
  bf16*  T4 = (bf16*)(wsb + 62220288);        //   524,288
  bf16*  WpE = Wp + (long)2048 * LAT_;

  prep_k<<<22618, 256, 0, stream>>>(g_iw, p_iw, p_cw, p_ow, f5,
      g_bg, g_bb, g_bm, g_bv, p_bg, p_bb, p_bm, p_bv, g_ib, p_ib, p_cb,
      g_ow, g_cw, f0, f1, f2, f3, f4,
      Wp, pcw16, pow16, T5, bnp, u, T0, T1, T2, T3, T4);
  sample5_k<<<dim3(66, 6, 8), 256, 0, stream>>>(T0, T1, T2, T3, T4, T5, P, Sb);
  nodegemm_k<<<dim3(32, 8), 256, 0, stream>>>(Sb, Wp, A4);
  edge_k<<<dim3(8, 8, 8), 256, 0, stream>>>(Sb, WpE, bnp, A4, XFh, DH);
  chorus_k<<<dim3(8, 4, 8), 256, 0, stream>>>(DH, pcw16, bnp, XFh, Yp16);
  outro_k<<<dim3(16, 1, 8), 256, 0, stream>>>(Yp16, pow16, p_ob, PR);
  final3_k<<<2048, 256, 0, stream>>>(XFh, DH, PR, u, g_ow, g_cb, g_ob, n, out);
}

// Round 8
// 256.789 us; speedup vs baseline: 1.3134x; 1.0330x over previous
//
#include <hip/hip_runtime.h>
#include <hip/hip_bf16.h>

using bf16 = __hip_bfloat16;
using short8 = __attribute__((ext_vector_type(8))) short;
using f32x4  = __attribute__((ext_vector_type(4))) float;
typedef unsigned int u32;

#define LAT_ 1536

__device__ __forceinline__ void glds16(const bf16* g, bf16* l) {
  __builtin_amdgcn_global_load_lds(
      (const __attribute__((address_space(1))) void*)g,
      (__attribute__((address_space(3))) void*)l, 16, 0, 0);
}
__device__ __forceinline__ float b2f(bf16 x) { return __bfloat162float(x); }
__device__ __forceinline__ bf16 f2b(float x) { return __float2bfloat16(x); }

// ---------------- NCHW fp32 -> NHWC bf16 tile ----------------
template<int C, int W>
__device__ __forceinline__ void trans_tile(const float* __restrict__ src, bf16* __restrict__ dst,
                                           int b, int hw0, int c0, bf16 (*tile)[72], int t) {
  constexpr int HW = W * W;
  {
    int cl = t >> 2, h0 = (t & 3) * 16;
    const float* sp = src + (long)(b * C + c0 + cl) * HW + hw0 + h0;
    #pragma unroll
    for (int k = 0; k < 16; k += 4) {
      float4 v = *(const float4*)(sp + k);
      tile[h0 + k + 0][cl] = f2b(v.x);
      tile[h0 + k + 1][cl] = f2b(v.y);
      tile[h0 + k + 2][cl] = f2b(v.z);
      tile[h0 + k + 3][cl] = f2b(v.w);
    }
  }
  __syncthreads();
  {
    int hwl = t >> 2, cc = (t & 3) * 16;
    bf16* dp = dst + ((long)b * HW + hw0 + hwl) * C + c0 + cc;
    #pragma unroll
    for (int k = 0; k < 16; k += 2) {
      __hip_bfloat162 pr;
      pr.x = tile[hwl][cc + k];
      pr.y = tile[hwl][cc + k + 1];
      *(__hip_bfloat162*)(dp + k) = pr;
    }
  }
}

// ---------------- fused prep ----------------
// [0,18432) packA | [18432,19456) pcw | [19456,19584) pow | [19584,19600) T5
// [19600,19602) bn | [19602,19610) u | [19610] gconst | [19611,19643) gacc=0
// [19643,22651) transposes
__global__ __launch_bounds__(256) void prep_k(
    const float* __restrict__ g_iw, const float* __restrict__ p_iw,
    const float* __restrict__ p_cw, const float* __restrict__ p_ow, const float* __restrict__ f5,
    const float* __restrict__ g_bg, const float* __restrict__ g_bb, const float* __restrict__ g_bm,
    const float* __restrict__ g_bv, const float* __restrict__ p_bg, const float* __restrict__ p_bb,
    const float* __restrict__ p_bm, const float* __restrict__ p_bv,
    const float* __restrict__ g_ib, const float* __restrict__ p_ib, const float* __restrict__ p_cb,
    const float* __restrict__ g_ow, const float* __restrict__ g_cw,
    const float* __restrict__ g_cb, const float* __restrict__ g_ob,
    const float* __restrict__ f0, const float* __restrict__ f1, const float* __restrict__ f2,
    const float* __restrict__ f3, const float* __restrict__ f4,
    bf16* __restrict__ Wp, bf16* __restrict__ pcw16, bf16* __restrict__ pow16,
    bf16* __restrict__ T5, float* __restrict__ bnp, float* __restrict__ u,
    float* __restrict__ gacc,
    bf16* __restrict__ T0, bf16* __restrict__ T1, bf16* __restrict__ T2,
    bf16* __restrict__ T3, bf16* __restrict__ T4) {
  __shared__ bf16 tile[64][72];
  __shared__ float red[256];
  int B = blockIdx.x, t = threadIdx.x;
  if (B < 18432) {
    int seg = B / 3072;
    int idx = (B % 3072) * 256 + t;
    if (idx < 512 * 1536) {
      int r = idx / 1536, c = idx % 1536;
      const float* src; int co;
      switch (seg) {
        case 0: src = g_iw; co = 0;    break;
        case 1: src = g_iw; co = 1536; break;
        case 2: src = p_iw; co = 0;    break;
        case 3: src = p_iw; co = 1536; break;
        case 4: src = g_iw; co = 3072; break;
        default: src = p_iw; co = 3072; break;
      }
      Wp[(long)seg * 512 * 1536 + idx] = f2b(src[(long)r * 4608 + co + c]);
    }
    return;
  }
  if (B < 19456) { int idx = (B - 18432) * 256 + t; pcw16[idx] = f2b(p_cw[idx]); return; }
  if (B < 19584) { int idx = (B - 19456) * 256 + t; pow16[idx] = f2b(p_ow[idx]); return; }
  if (B < 19600) { int idx = (B - 19584) * 256 + t; T5[idx] = f2b(f5[idx]); return; }
  if (B < 19602) {
    int k = (B - 19600) * 256 + t;
    if (k < 512) {
      float sg = g_bg[k] / sqrtf(g_bv[k] + 1e-5f);
      bnp[k] = sg; bnp[512 + k] = g_bb[k] - g_bm[k] * sg;
      float sp = p_bg[k] / sqrtf(p_bv[k] + 1e-5f);
      bnp[1024 + k] = sp; bnp[1536 + k] = p_bb[k] - p_bm[k] * sp;
      bnp[2048 + k] = g_ib[k]; bnp[2560 + k] = p_ib[k];
      bnp[3584 + k] = p_cb[k];
    }
    return;
  }
  if (B < 19610) {                      // u[k] = sum_o g_ow[o]*g_cw[o*512+k]
    __shared__ float ured[4][64];
    int k0 = (B - 19602) * 64;
    int kk = t & 63, part = t >> 6;
    int k = k0 + kk;
    float s = 0.f;
    for (int o = part * 128; o < part * 128 + 128; ++o)
      s = fmaf(g_ow[o], g_cw[o * 512 + k], s);
    ured[part][kk] = s;
    __syncthreads();
    if (part == 0) u[k] = ured[0][kk] + ured[1][kk] + ured[2][kk] + ured[3][kk];
    return;
  }
  if (B == 19610) {                     // gconst = sum g_ow*g_cb + g_ob
    red[t] = g_ow[t] * g_cb[t] + g_ow[t + 256] * g_cb[t + 256];
    __syncthreads();
    for (int off = 128; off; off >>= 1) {
      if (t < off) red[t] += red[t + off];
      __syncthreads();
    }
    if (t == 0) bnp[3072] = red[0] + g_ob[0];
    return;
  }
  if (B < 19643) { int idx = (B - 19611) * 256 + t; gacc[idx] = 0.f; return; }
  {
    int q = B - 19643;
    int b = q / 376, tt = q % 376;
    if (tt < 256)      trans_tile<64, 128>(f0, T0, b, tt * 64, 0, tile, t);
    else if (tt < 320) trans_tile<64, 64 >(f1, T1, b, (tt - 256) * 64, 0, tile, t);
    else if (tt < 352) { int z = tt - 320; trans_tile<128, 32>(f2, T2, b, (z & 15) * 64, (z >> 4) * 64, tile, t); }
    else if (tt < 368) { int z = tt - 352; trans_tile<256, 16>(f3, T3, b, (z & 3) * 64, (z >> 2) * 64, tile, t); }
    else               { int z = tt - 368; trans_tile<512, 8 >(f4, T4, b, 0, z * 64, tile, t); }
  }
}

// ---------------- sampling ----------------
__device__ __forceinline__ float blo(u32 r) { return __uint_as_float(r << 16); }
__device__ __forceinline__ float bhi(u32 r) { return __uint_as_float(r & 0xffff0000u); }

template<int C, int W>
__device__ __forceinline__ void proc2(const bf16* __restrict__ T, int b,
    const float* MX, const float* MY, bf16* __restrict__ Sb, int koff, int t) {
  constexpr int C2 = C / 2, HW = W * W;
  const bf16* Tb = T + (long)b * HW * C;
  for (int idx = t; idx < 16 * C2; idx += 256) {
    int q = idx / C2, c2 = idx % C2;
    float x = MX[q], y = MY[q];
    float fx = fminf(fmaxf(x * ((float)W / 256.f) - 0.5f, 0.f), (float)(W - 1));
    float fy = fminf(fmaxf(y * ((float)W / 256.f) - 0.5f, 0.f), (float)(W - 1));
    float x0f = floorf(fx), y0f = floorf(fy);
    float wx = fx - x0f, wy = fy - y0f;
    int x0 = (int)x0f, y0 = (int)y0f;
    int x1 = min(x0 + 1, W - 1), y1 = min(y0 + 1, W - 1);
    u32 r00 = *(const u32*)&Tb[(y0 * W + x0) * C + 2 * c2];
    u32 r01 = *(const u32*)&Tb[(y0 * W + x1) * C + 2 * c2];
    u32 r10 = *(const u32*)&Tb[(y1 * W + x0) * C + 2 * c2];
    u32 r11 = *(const u32*)&Tb[(y1 * W + x1) * C + 2 * c2];
    float w00 = (1.f - wx) * (1.f - wy), w01 = wx * (1.f - wy);
    float w10 = (1.f - wx) * wy,        w11 = wx * wy;
    float vlo = blo(r00) * w00 + blo(r01) * w01 + blo(r10) * w10 + blo(r11) * w11;
    float vhi = bhi(r00) * w00 + bhi(r01) * w01 + bhi(r10) * w10 + bhi(r11) * w11;
    __hip_bfloat162 pr;
    pr.x = f2b(vlo); pr.y = f2b(vhi);
    *(__hip_bfloat162*)&Sb[(long)q * LAT_ + koff + 2 * c2] = pr;
  }
}

__global__ __launch_bounds__(256) void sample5_k(
    const bf16* __restrict__ T0, const bf16* __restrict__ T1, const bf16* __restrict__ T2,
    const bf16* __restrict__ T3, const bf16* __restrict__ T4, const bf16* __restrict__ T5,
    const float* __restrict__ P, bf16* __restrict__ Sball) {
  int b = blockIdx.z, p0 = blockIdx.x * 16, lvl = blockIdx.y, t = threadIdx.x;
  __shared__ float Px[32], Py[32], MX[16], MY[16];
  if (t < 32) { Px[t] = P[(b * 32 + t) * 2]; Py[t] = P[(b * 32 + t) * 2 + 1]; }
  __syncthreads();
  if (t < 16) {
    int m = p0 + t;
    float x, y;
    if (m < 32) { x = Px[m]; y = Py[m]; }
    else { int ij = m - 32, i = ij >> 5, j = ij & 31;
           x = 0.5f * (Px[i] + Px[j]); y = 0.5f * (Py[i] + Py[j]); }
    MX[t] = x; MY[t] = y;
  }
  __syncthreads();
  bf16* Sb = Sball + ((long)b * 1056 + p0) * LAT_;
  switch (lvl) {
    case 0: proc2<64, 128>(T0, b, MX, MY, Sb, 0,    t); break;
    case 1: proc2<64, 64 >(T1, b, MX, MY, Sb, 64,   t); break;
    case 2: proc2<128, 32>(T2, b, MX, MY, Sb, 128,  t); break;
    case 3: proc2<256, 16>(T3, b, MX, MY, Sb, 256,  t); break;
    case 4: proc2<512, 8 >(T4, b, MX, MY, Sb, 512,  t); break;
    default:
      for (int idx = t; idx < 16 * 256; idx += 256) {
        int q = idx >> 8, c2 = idx & 255;
        *(__hip_bfloat162*)&Sb[(long)q * LAT_ + 1024 + 2 * c2] =
            *(const __hip_bfloat162*)&T5[b * 512 + 2 * c2];
      }
  }
}

// ---------------- node GEMM: A4[b][32][2048] ----------------
__global__ __launch_bounds__(256) void nodegemm_k(
    const bf16* __restrict__ Sball, const bf16* __restrict__ Wp, float* __restrict__ A4) {
  int b = blockIdx.y;
  int n0 = blockIdx.x * 64;
  int t = threadIdx.x, w = t >> 6, lane = t & 63;
  int nn = n0 + w * 16;
  int frow = lane & 15, fko = (lane >> 4) * 8;
  const bf16* Ab = Sball + (long)b * 1056 * LAT_;
  f32x4 acc[2] = {};
  for (int kb = 0; kb < LAT_; kb += 32) {
    short8 bq = *(const short8*)&Wp[(long)(nn + frow) * LAT_ + kb + fko];
    #pragma unroll
    for (int i = 0; i < 2; ++i) {
      short8 aq = *(const short8*)&Ab[(long)(i * 16 + frow) * LAT_ + kb + fko];
      acc[i] = __builtin_amdgcn_mfma_f32_16x16x32_bf16(aq, bq, acc[i], 0, 0, 0);
    }
  }
  #pragma unroll
  for (int i = 0; i < 2; ++i)
    #pragma unroll
    for (int r = 0; r < 4; ++r) {
      int m = i * 16 + (lane >> 4) * 4 + r;
      int n = nn + (lane & 15);
      A4[(long)b * 65536 + m * 2048 + n] = acc[i][r];
    }
}

// ---------------- edge GEMM: M=1024, N=1024 (g|p), K=1536 ----------------
// g n-tiles (n<512): gate partials -> atomicAdd gacc[b][m]
// p n-tiles (n>=512): store compact XFh/DH [m][512]
__global__ __launch_bounds__(256) void edge_k(
    const bf16* __restrict__ Sball, const bf16* __restrict__ WpE,
    const float* __restrict__ bnp, const float* __restrict__ A4,
    const float* __restrict__ u, const float* __restrict__ g_ow,
    bf16* __restrict__ XFh, bf16* __restrict__ DH, float* __restrict__ gacc) {
  int b = blockIdx.z;
  int m0 = blockIdx.x * 128, n0 = blockIdx.y * 128;
  const bf16* A = Sball + (long)b * 1056 * LAT_ + 32 * LAT_;
  __shared__ bf16 Ash[128 * 32];
  __shared__ bf16 Bsh[128 * 32];
  int t = threadIdx.x, w = t >> 6, lane = t & 63;
  int mh = (w & 1) * 64, nh = (w >> 1) * 64;
  int frow = lane & 15, fko = (lane >> 4) * 8;
  int lrow = lane >> 2, lchunk = lane & 3;
  f32x4 acc[4][4] = {};
  for (int kb = 0; kb < LAT_; kb += 32) {
    #pragma unroll
    for (int q = 0; q < 2; ++q) {
      int ra = q * 64 + w * 16 + lrow;
      glds16(&A[(long)(m0 + ra) * LAT_ + kb + lchunk * 8],   &Ash[ra * 32 + lchunk * 8]);
      glds16(&WpE[(long)(n0 + ra) * LAT_ + kb + lchunk * 8], &Bsh[ra * 32 + lchunk * 8]);
    }
    __syncthreads();
    short8 af[4], bq[4];
    #pragma unroll
    for (int i = 0; i < 4; ++i) af[i] = *(const short8*)&Ash[(mh + i * 16 + frow) * 32 + fko];
    #pragma unroll
    for (int j = 0; j < 4; ++j) bq[j] = *(const short8*)&Bsh[(nh + j * 16 + frow) * 32 + fko];
    #pragma unroll
    for (int i = 0; i < 4; ++i)
      #pragma unroll
      for (int j = 0; j < 4; ++j)
        acc[i][j] = __builtin_amdgcn_mfma_f32_16x16x32_bf16(af[i], bq[j], acc[i][j], 0, 0, 0);
    __syncthreads();
  }
  if (n0 < 512) {                                     // gate half
    float pg[16];
    #pragma unroll
    for (int z = 0; z < 16; ++z) pg[z] = 0.f;
    #pragma unroll
    for (int i = 0; i < 4; ++i) {
      #pragma unroll
      for (int j = 0; j < 4; ++j) {
        int n = n0 + nh + j * 16 + (lane & 15);
        float gw = g_ow[n], uu = u[n];
        float sc = bnp[n], sh = bnp[512 + n], ib = bnp[2048 + n];
        #pragma unroll
        for (int r = 0; r < 4; ++r) {
          int m = m0 + mh + i * 16 + (lane >> 4) * 4 + r;
          float v = acc[i][j][r] + ib
                  + A4[((long)b * 32 + (m >> 5)) * 2048 + n]
                  + A4[((long)b * 32 + (m & 31)) * 2048 + 512 + n];
          float d = fmaxf(fmaf(v, sc, sh), 0.f);
          pg[i * 4 + r] += gw * v + uu * d;
        }
      }
    }
    #pragma unroll
    for (int z = 0; z < 16; ++z) {
      float v = pg[z];
      v += __shfl_xor(v, 1, 16);
      v += __shfl_xor(v, 2, 16);
      v += __shfl_xor(v, 4, 16);
      v += __shfl_xor(v, 8, 16);
      pg[z] = v;
    }
    if ((lane & 15) == 0) {
      #pragma unroll
      for (int z = 0; z < 16; ++z) {
        int m = m0 + mh + (z >> 2) * 16 + (lane >> 4) * 4 + (z & 3);
        atomicAdd(&gacc[(long)b * 1024 + m], pg[z]);
      }
    }
  } else {                                            // p half: store compact
    #pragma unroll
    for (int i = 0; i < 4; ++i) {
      #pragma unroll
      for (int j = 0; j < 4; ++j) {
        int n = n0 + nh + j * 16 + (lane & 15);
        int np = n - 512;
        float sc = bnp[1024 + np], sh = bnp[1536 + np], ib = bnp[2048 + n];
        #pragma unroll
        for (int r = 0; r < 4; ++r) {
          int m = m0 + mh + i * 16 + (lane >> 4) * 4 + r;
          float v = acc[i][j][r] + ib
                  + A4[((long)b * 32 + (m >> 5)) * 2048 + 1024 + np]
                  + A4[((long)b * 32 + (m & 31)) * 2048 + 1536 + np];
          long e = ((long)b * 1024 + m) * 512 + np;
          XFh[e] = f2b(v);
          DH[e]  = f2b(fmaxf(fmaf(v, sc, sh), 0.f));
        }
      }
    }
  }
}

// ---------------- chorus-p (compact), Yp16 = XFh + pcw @ DH + p_cb ----------------
__global__ __launch_bounds__(256) void chorus_k(
    const bf16* __restrict__ DH, const bf16* __restrict__ pcw16,
    const float* __restrict__ bnp, const bf16* __restrict__ XFh,
    bf16* __restrict__ Yp16) {
  int b = blockIdx.z;
  int m0 = blockIdx.x * 128, n0 = blockIdx.y * 128;
  const bf16* A = DH + (long)b * 1024 * 512;
  __shared__ bf16 Ash[128 * 32];
  __shared__ bf16 Bsh[128 * 32];
  int t = threadIdx.x, w = t >> 6, lane = t & 63;
  int mh = (w & 1) * 64, nh = (w >> 1) * 64;
  int frow = lane & 15, fko = (lane >> 4) * 8;
  int lrow = lane >> 2, lchunk = lane & 3;
  f32x4 acc[4][4] = {};
  for (int kb = 0; kb < 512; kb += 32) {
    #pragma unroll
    for (int q = 0; q < 2; ++q) {
      int ra = q * 64 + w * 16 + lrow;
      glds16(&A[(long)(m0 + ra) * 512 + kb + lchunk * 8],      &Ash[ra * 32 + lchunk * 8]);
      glds16(&pcw16[(long)(n0 + ra) * 512 + kb + lchunk * 8],  &Bsh[ra * 32 + lchunk * 8]);
    }
    __syncthreads();
    short8 af[4], bq[4];
    #pragma unroll
    for (int i = 0; i < 4; ++i) af[i] = *(const short8*)&Ash[(mh + i * 16 + frow) * 32 + fko];
    #pragma unroll
    for (int j = 0; j < 4; ++j) bq[j] = *(const short8*)&Bsh[(nh + j * 16 + frow) * 32 + fko];
    #pragma unroll
    for (int i = 0; i < 4; ++i)
      #pragma unroll
      for (int j = 0; j < 4; ++j)
        acc[i][j] = __builtin_amdgcn_mfma_f32_16x16x32_bf16(af[i], bq[j], acc[i][j], 0, 0, 0);
    __syncthreads();
  }
  #pragma unroll
  for (int i = 0; i < 4; ++i)
    #pragma unroll
    for (int j = 0; j < 4; ++j)
      #pragma unroll
      for (int r = 0; r < 4; ++r) {
        int m = m0 + mh + i * 16 + (lane >> 4) * 4 + r;
        int n = n0 + nh + j * 16 + (lane & 15);
        float v = acc[i][j][r] + bnp[3584 + n]
                + b2f(XFh[((long)b * 1024 + m) * 512 + n]);
        Yp16[((long)b * 1024 + m) * 512 + n] = f2b(v);
      }
}

// ---------------- fused outro + final ----------------
__global__ __launch_bounds__(256) void ofinal_k(
    const bf16* __restrict__ Yp16, const bf16* __restrict__ pow16,
    const float* __restrict__ p_ob, const float* __restrict__ gacc,
    const float* __restrict__ bnp, const int* __restrict__ nvec,
    float* __restrict__ out) {
  int b = blockIdx.y;
  int m0 = blockIdx.x * 64;
  const bf16* Ab = Yp16 + (long)b * 1024 * 512;
  __shared__ bf16 Ash[64][40];
  __shared__ bf16 Bsh[64][40];
  __shared__ float ol[64][65];
  int t = threadIdx.x, w = t >> 6, lane = t & 63;
  int mq = w * 16;
  int frow = lane & 15, fko = (lane >> 4) * 8;
  f32x4 acc[4] = {};
  for (int kb = 0; kb < 512; kb += 32) {
    { int r = t >> 2, ko = (t & 3) * 8;
      *(uint4*)&Ash[r][ko] = *(const uint4*)&Ab[(long)(m0 + r) * 512 + kb + ko];
      *(uint4*)&Bsh[r][ko] = *(const uint4*)&pow16[(long)r * 512 + kb + ko]; }
    __syncthreads();
    short8 af = *(const short8*)&Ash[mq + frow][fko];
    #pragma unroll
    for (int j = 0; j < 4; ++j) {
      short8 bq = *(const short8*)&Bsh[j * 16 + frow][fko];
      acc[j] = __builtin_amdgcn_mfma_f32_16x16x32_bf16(af, bq, acc[j], 0, 0, 0);
    }
    __syncthreads();
  }
  float pr[4][4], ssl[4] = {0.f, 0.f, 0.f, 0.f};
  #pragma unroll
  for (int j = 0; j < 4; ++j) {
    float bias = p_ob[j * 16 + (lane & 15)];
    #pragma unroll
    for (int r = 0; r < 4; ++r) {
      float v = acc[j][r] + bias;
      pr[j][r] = v;
      ssl[r] = fmaf(v, v, ssl[r]);
    }
  }
  #pragma unroll
  for (int r = 0; r < 4; ++r) {
    float v = ssl[r];
    v += __shfl_xor(v, 1, 16);
    v += __shfl_xor(v, 2, 16);
    v += __shfl_xor(v, 4, 16);
    v += __shfl_xor(v, 8, 16);
    ssl[r] = v;
  }
  int nb = nvec[b];
  float gconst = bnp[3072];
  float scale[4];
  #pragma unroll
  for (int r = 0; r < 4; ++r) {
    int m = m0 + mq + (lane >> 4) * 4 + r;
    float gl = gacc[(long)b * 1024 + m] + gconst;
    float gate = 1.f / (1.f + expf(-gl));
    int ii = m >> 5, jj = m & 31;
    float maskv = (ii < nb && jj < nb) ? 1.f : 0.f;
    scale[r] = gate * maskv / fmaxf(sqrtf(ssl[r]), 1e-12f);
  }
  #pragma unroll
  for (int j = 0; j < 4; ++j)
    #pragma unroll
    for (int r = 0; r < 4; ++r)
      ol[mq + (lane >> 4) * 4 + r][j * 16 + (lane & 15)] = pr[j][r] * scale[r];
  __syncthreads();
  {
    int c = t >> 2, ms = (t & 3) * 16;
    float* op = out + ((long)b * 64 + c) * 1024 + m0 + ms;
    #pragma unroll
    for (int k = 0; k < 16; k += 4) {
      float4 v;
      v.x = ol[ms + k + 0][c];
      v.y = ol[ms + k + 1][c];
      v.z = ol[ms + k + 2][c];
      v.w = ol[ms + k + 3][c];
      *(float4*)(op + k) = v;
    }
  }
}

extern "C" void kernel_launch(void* const* d_in, const int* in_sizes, int n_in,
                              void* d_out, int out_size, void* d_ws, size_t ws_size,
                              hipStream_t stream) {
  const float* f0 = (const float*)d_in[0];
  const float* f1 = (const float*)d_in[1];
  const float* f2 = (const float*)d_in[2];
  const float* f3 = (const float*)d_in[3];
  const float* f4 = (const float*)d_in[4];
  const float* f5 = (const float*)d_in[5];
  const float* P  = (const float*)d_in[6];
  const int*   n  = (const int*)d_in[7];
  const float *g_iw=(const float*)d_in[8],  *g_ib=(const float*)d_in[9],
              *g_bg=(const float*)d_in[10], *g_bb=(const float*)d_in[11],
              *g_bm=(const float*)d_in[12], *g_bv=(const float*)d_in[13],
              *g_cw=(const float*)d_in[14], *g_cb=(const float*)d_in[15],
              *g_ow=(const float*)d_in[16], *g_ob=(const float*)d_in[17];
  const float *p_iw=(const float*)d_in[18], *p_ib=(const float*)d_in[19],
              *p_bg=(const float*)d_in[20], *p_bb=(const float*)d_in[21],
              *p_bm=(const float*)d_in[22], *p_bv=(const float*)d_in[23],
              *p_cw=(const float*)d_in[24], *p_cb=(const float*)d_in[25],
              *p_ow=(const float*)d_in[26], *p_ob=(const float*)d_in[27];
  float* out = (float*)d_out;
  char* wsb = (char*)d_ws;

  // workspace (byte offsets)
  bf16*  Sb    = (bf16*)(wsb + 0);            // 25,952,256
  bf16*  Wp    = (bf16*)(wsb + 25952256);     // 9,437,184  -> 35,389,440
  bf16*  pcw16 = (bf16*)(wsb + 35389440);     // 524,288    -> 35,913,728
  bf16*  pow16 = (bf16*)(wsb + 35913728);     // 65,536     -> 35,979,264
  bf16*  T5    = (bf16*)(wsb + 35979264);     // 8,192      -> 35,987,456
  float* bnp   = (float*)(wsb + 35987456);    // 16,384     -> 36,003,840
  float* u     = (float*)(wsb + 36003840);    // 2,048      -> 36,005,888
  float* gacc  = (float*)(wsb + 36005888);    // 32,768     -> 36,038,656
  float* A4    = (float*)(wsb + 36038656);    // 2,097,152  -> 38,135,808
  bf16*  XFh   = (bf16*)(wsb + 38135808);     // 8,388,608  -> 46,524,416
  bf16*  DH    = (bf16*)(wsb + 46524416);     // 8,388,608  -> 54,913,024
  bf16*  Yp16  = (bf16*)(wsb + 54913024);     // 8,388,608  -> 63,301,632
  // T0..T4 overlay XFh/DH/Yp16 + tail (dead until edge_k)
  bf16*  T0 = (bf16*)(wsb + 38135808);        // 16,777,216 (over XFh+DH)
  bf16*  T1 = (bf16*)(wsb + 54913024);        // 4,194,304  (over Yp16)
  bf16*  T2 = (bf16*)(wsb + 59107328);        // 2,097,152
  bf16*  T3 = (bf16*)(wsb + 61204480);        // 1,048,576
  bf16*  T4 = (bf16*)(wsb + 62253056);        //   524,288  -> 62,777,344
  bf16*  WpE = Wp + (long)2048 * LAT_;

  prep_k<<<22651, 256, 0, stream>>>(g_iw, p_iw, p_cw, p_ow, f5,
      g_bg, g_bb, g_bm, g_bv, p_bg, p_bb, p_bm, p_bv, g_ib, p_ib, p_cb,
      g_ow, g_cw, g_cb, g_ob, f0, f1, f2, f3, f4,
      Wp, pcw16, pow16, T5, bnp, u, gacc, T0, T1, T2, T3, T4);
  sample5_k<<<dim3(66, 6, 8), 256, 0, stream>>>(T0, T1, T2, T3, T4, T5, P, Sb);
  nodegemm_k<<<dim3(32, 8), 256, 0, stream>>>(Sb, Wp, A4);
  edge_k<<<dim3(8, 8, 8), 256, 0, stream>>>(Sb, WpE, bnp, A4, u, g_ow, XFh, DH, gacc);
  chorus_k<<<dim3(8, 4, 8), 256, 0, stream>>>(DH, pcw16, bnp, XFh, Yp16);
  ofinal_k<<<dim3(16, 8), 256, 0, stream>>>(Yp16, pow16, p_ob, gacc, bnp, n, out);
}